// Round 7
// baseline (272.543 us; speedup 1.0000x reference)
//
#include <hip/hip_runtime.h>

#define NB 256      // dst-range buckets
#define CHUNK 8192  // edges per partition block
// pack: code = (dl<<17)|src ; valid because N=100000<2^17 and capN=391<2^9

// ---------------- phase 1: partition edges into dst-range buckets ----------------
__global__ void k_part(const int* __restrict__ srcI, const int* __restrict__ dstI,
                       int* __restrict__ gcur, int* __restrict__ pairs,
                       int E, int N, int capN, int capE) {
  __shared__ int hist[NB];
  __shared__ int base[NB];
  __shared__ int cnt[NB];
  int tid = threadIdx.x;  // 256
  int e0 = blockIdx.x * CHUNK;
  int eend = min(e0 + CHUNK, E);
  hist[tid] = 0;
  __syncthreads();
  for (int e = e0 + tid; e < eend; e += 256) {
    int d = dstI[e];
    if ((unsigned)d < (unsigned)N) atomicAdd(&hist[d / capN], 1);
  }
  __syncthreads();
  base[tid] = tid * capE + atomicAdd(&gcur[tid], hist[tid]);
  cnt[tid] = 0;
  __syncthreads();
  for (int e = e0 + tid; e < eend; e += 256) {
    int d = dstI[e];
    int s = srcI[e];
    if ((unsigned)d < (unsigned)N && (unsigned)s < (unsigned)N) {
      int b = d / capN;
      int slot = base[b] + atomicAdd(&cnt[b], 1);
      if (slot < (b + 1) * capE)
        pairs[slot] = ((d - b * capN) << 17) | s;
    }
  }
}

// ---------------- phase 2: per-bucket CSR build ----------------
__launch_bounds__(512)
__global__ void k_csr(const int* __restrict__ pairs, const int* __restrict__ gcur,
                      int* __restrict__ deg, int* __restrict__ rowoff,
                      int* __restrict__ csr, int N, int capN, int capE) {
  __shared__ int hist[512];
  __shared__ int tmp[512];
  __shared__ int cur[512];
  int q = blockIdx.x;
  int tid = threadIdx.x;
  int nloc = N - q * capN;
  if (nloc > capN) nloc = capN;
  int base = q * capE;
  int cnt = gcur[q];
  if (cnt > capE) cnt = capE;
  int qbase = q * capN;
  hist[tid] = 0;
  __syncthreads();
  for (int e = tid; e < cnt; e += 512) {
    int code = pairs[base + e];
    int dl = (unsigned)code >> 17;
    if (dl < nloc) atomicAdd(&hist[dl], 1);
  }
  __syncthreads();
  int v = hist[tid];
  tmp[tid] = v;
  __syncthreads();
  for (int off = 1; off < 512; off <<= 1) {
    int t = (tid >= off) ? tmp[tid - off] : 0;
    __syncthreads();
    tmp[tid] += t;
    __syncthreads();
  }
  int ex = tmp[tid] - v;
  cur[tid] = ex;
  if (tid < nloc) {
    int i = qbase + tid;
    deg[i] = v;
    rowoff[i] = base + ex;
  }
  __syncthreads();
  for (int e = tid; e < cnt; e += 512) {
    int code = pairs[base + e];
    int dl = (unsigned)code >> 17;
    if (dl < nloc) {
      int pos = atomicAdd(&cur[dl], 1);
      csr[base + pos] = code & 0x1FFFF;
    }
  }
}

// ---------------- fused layer1: aggregate tile into LDS + GEMM --------------------
// 64-row tile, 256 thr. Phase 1: wave w aggregates rows w*16..w*16+15 into sM
// (transposed [k][row], stride 68). Phase 2: GEMM h = relu([m|x]@[W1l;W1r]+b1),
// A from LDS (sM / staged sX), W from global (L2-hot, keeps LDS small).
__launch_bounds__(256, 4)
__global__ void k_aggh(const float* __restrict__ x, const int* __restrict__ csr,
                       const int* __restrict__ rowoff, const int* __restrict__ deg,
                       const float* __restrict__ W1l, const float* __restrict__ W1r,
                       const float* __restrict__ b1, float* __restrict__ h, int n) {
  __shared__ float sM[64 * 68];   // aggregated m-tile, [kdim][localrow]
  __shared__ float sX[32 * 68];   // x kt-tile staging, [kdim][localrow]
  int tid = threadIdx.x;
  int row0 = blockIdx.x * 64;
  int wid = tid >> 6;
  int lane = tid & 63;

  // ---- phase 1: mean-aggregate 16 rows per wave ----
  for (int r16 = 0; r16 < 16; ++r16) {
    int row = row0 + wid * 16 + r16;
    if (row >= n) break;
    int start = __builtin_amdgcn_readfirstlane(rowoff[row]);
    int d = __builtin_amdgcn_readfirstlane(deg[row]);
    float a0 = 0.f, a1 = 0.f, a2 = 0.f, a3 = 0.f;
    float a4 = 0.f, a5 = 0.f, a6 = 0.f, a7 = 0.f;
    int j = 0;
    for (; j + 7 < d; j += 8) {
      int s0 = csr[start + j], s1 = csr[start + j + 1];
      int s2 = csr[start + j + 2], s3 = csr[start + j + 3];
      int s4 = csr[start + j + 4], s5 = csr[start + j + 5];
      int s6 = csr[start + j + 6], s7 = csr[start + j + 7];
      a0 += x[(size_t)s0 * 64 + lane]; a1 += x[(size_t)s1 * 64 + lane];
      a2 += x[(size_t)s2 * 64 + lane]; a3 += x[(size_t)s3 * 64 + lane];
      a4 += x[(size_t)s4 * 64 + lane]; a5 += x[(size_t)s5 * 64 + lane];
      a6 += x[(size_t)s6 * 64 + lane]; a7 += x[(size_t)s7 * 64 + lane];
    }
    for (; j + 3 < d; j += 4) {
      int s0 = csr[start + j], s1 = csr[start + j + 1];
      int s2 = csr[start + j + 2], s3 = csr[start + j + 3];
      a0 += x[(size_t)s0 * 64 + lane]; a1 += x[(size_t)s1 * 64 + lane];
      a2 += x[(size_t)s2 * 64 + lane]; a3 += x[(size_t)s3 * 64 + lane];
    }
    for (; j < d; ++j) a0 += x[(size_t)csr[start + j] * 64 + lane];
    float inv = (d > 0) ? 1.f / (float)d : 0.f;
    sM[lane * 68 + wid * 16 + r16] =
        (((a0 + a1) + (a2 + a3)) + ((a4 + a5) + (a6 + a7))) * inv;
  }
  __syncthreads();

  // ---- phase 2: GEMM ----
  int colT = tid & 15;
  int rowT = tid >> 4;
  float acc[4][4];
#pragma unroll
  for (int r = 0; r < 4; ++r)
#pragma unroll
    for (int c = 0; c < 4; ++c) acc[r][c] = 0.f;

  for (int kt = 0; kt < 4; ++kt) {
    const float* wsrc = (kt < 2) ? W1l : W1r;
    int ko = (kt & 1) * 32;
    const float* abase;
    if (kt < 2) {
      abase = &sM[ko * 68];
    } else {
      __syncthreads();  // protect sX from previous kt's readers
      int f = tid;
#pragma unroll
      for (int i = 0; i < 2; ++i, f += 256) {
        int r = f >> 3, kq = f & 7;
        int rr = row0 + r; if (rr > n - 1) rr = n - 1;
        float4 v = *(const float4*)(x + (size_t)rr * 64 + ko + kq * 4);
        sX[(kq * 4 + 0) * 68 + r] = v.x;
        sX[(kq * 4 + 1) * 68 + r] = v.y;
        sX[(kq * 4 + 2) * 68 + r] = v.z;
        sX[(kq * 4 + 3) * 68 + r] = v.w;
      }
      __syncthreads();
      abase = sX;
    }
#pragma unroll 4
    for (int k = 0; k < 32; ++k) {
      float4 a = *(const float4*)&abase[k * 68 + rowT * 4];
      float4 w = *(const float4*)(wsrc + (size_t)(ko + k) * 64 + colT * 4);
      acc[0][0] += a.x * w.x; acc[0][1] += a.x * w.y; acc[0][2] += a.x * w.z; acc[0][3] += a.x * w.w;
      acc[1][0] += a.y * w.x; acc[1][1] += a.y * w.y; acc[1][2] += a.y * w.z; acc[1][3] += a.y * w.w;
      acc[2][0] += a.z * w.x; acc[2][1] += a.z * w.y; acc[2][2] += a.z * w.z; acc[2][3] += a.z * w.w;
      acc[3][0] += a.w * w.x; acc[3][1] += a.w * w.y; acc[3][2] += a.w * w.z; acc[3][3] += a.w * w.w;
    }
  }
  float4 bb = *(const float4*)(b1 + colT * 4);
#pragma unroll
  for (int r = 0; r < 4; ++r) {
    int row = row0 + rowT * 4 + r;
    if (row < n) {
      float4 o;
      o.x = fmaxf(acc[r][0] + bb.x, 0.f);
      o.y = fmaxf(acc[r][1] + bb.y, 0.f);
      o.z = fmaxf(acc[r][2] + bb.z, 0.f);
      o.w = fmaxf(acc[r][3] + bb.w, 0.f);
      *(float4*)(h + (size_t)row * 64 + colT * 4) = o;
    }
  }
}

// ---------------- layer2 GEMM: [p|q] = h @ [W2l|W2r] ------------------------------
__launch_bounds__(256, 4)
__global__ void k_pq(const float* __restrict__ h, const float* __restrict__ W2l,
                     const float* __restrict__ W2r, float* __restrict__ p,
                     float* __restrict__ q, int n) {
  __shared__ float sAT[32 * 132];
  __shared__ float sW[32 * 32];
  int tid = threadIdx.x;
  int row0 = blockIdx.x * 128;
  int colT = tid & 7;
  int rowT = tid >> 3;
  float acc[4][4];
#pragma unroll
  for (int r = 0; r < 4; ++r)
#pragma unroll
    for (int c = 0; c < 4; ++c) acc[r][c] = 0.f;

  for (int kt = 0; kt < 2; ++kt) {
    int ko = kt * 32;
    __syncthreads();
    {
      int f = tid;
#pragma unroll
      for (int i = 0; i < 4; ++i, f += 256) {
        int r = f >> 3, kq = f & 7;
        int rr = row0 + r; if (rr > n - 1) rr = n - 1;
        float4 v = *(const float4*)(h + (size_t)rr * 64 + ko + kq * 4);
        sAT[(kq * 4 + 0) * 132 + r] = v.x;
        sAT[(kq * 4 + 1) * 132 + r] = v.y;
        sAT[(kq * 4 + 2) * 132 + r] = v.z;
        sAT[(kq * 4 + 3) * 132 + r] = v.w;
      }
      int wr = tid >> 3, cq = tid & 7;
      const float* wsrc = (cq < 4) ? W2l : W2r;
      int cc = (cq & 3) * 4;
      float4 v = *(const float4*)(wsrc + (size_t)(ko + wr) * 16 + cc);
      *(float4*)&sW[wr * 32 + cq * 4] = v;
    }
    __syncthreads();
#pragma unroll 4
    for (int k = 0; k < 32; ++k) {
      float4 a = *(const float4*)&sAT[k * 132 + rowT * 4];
      float4 w = *(const float4*)&sW[k * 32 + colT * 4];
      acc[0][0] += a.x * w.x; acc[0][1] += a.x * w.y; acc[0][2] += a.x * w.z; acc[0][3] += a.x * w.w;
      acc[1][0] += a.y * w.x; acc[1][1] += a.y * w.y; acc[1][2] += a.y * w.z; acc[1][3] += a.y * w.w;
      acc[2][0] += a.z * w.x; acc[2][1] += a.z * w.y; acc[2][2] += a.z * w.z; acc[2][3] += a.z * w.w;
      acc[3][0] += a.w * w.x; acc[3][1] += a.w * w.y; acc[3][2] += a.w * w.z; acc[3][3] += a.w * w.w;
    }
  }
#pragma unroll
  for (int r = 0; r < 4; ++r) {
    int row = row0 + rowT * 4 + r;
    if (row < n) {
      float* dst = (colT < 4) ? (p + (size_t)row * 16 + colT * 4)
                              : (q + (size_t)row * 16 + (colT - 4) * 4);
      *(float4*)dst = make_float4(acc[r][0], acc[r][1], acc[r][2], acc[r][3]);
    }
  }
}

// ---------------- mean aggregate 16-dim + epilogue: out = mean(p_nbr) + q + b2 ----
__global__ void k_agg16(const float* __restrict__ p, const int* __restrict__ csr,
                        const int* __restrict__ rowoff, const int* __restrict__ deg,
                        const float* __restrict__ b2, float* __restrict__ out, int n) {
  int t = blockIdx.x * blockDim.x + threadIdx.x;
  int i = t >> 4;
  int dd = t & 15;
  if (i >= n) return;
  int start = rowoff[i];
  int d = deg[i];
  float a0 = 0.f, a1 = 0.f, a2 = 0.f, a3 = 0.f;
  float a4 = 0.f, a5 = 0.f, a6 = 0.f, a7 = 0.f;
  int j = 0;
  for (; j + 7 < d; j += 8) {
    int s0 = csr[start + j], s1 = csr[start + j + 1];
    int s2 = csr[start + j + 2], s3 = csr[start + j + 3];
    int s4 = csr[start + j + 4], s5 = csr[start + j + 5];
    int s6 = csr[start + j + 6], s7 = csr[start + j + 7];
    a0 += p[(size_t)s0 * 16 + dd]; a1 += p[(size_t)s1 * 16 + dd];
    a2 += p[(size_t)s2 * 16 + dd]; a3 += p[(size_t)s3 * 16 + dd];
    a4 += p[(size_t)s4 * 16 + dd]; a5 += p[(size_t)s5 * 16 + dd];
    a6 += p[(size_t)s6 * 16 + dd]; a7 += p[(size_t)s7 * 16 + dd];
  }
  for (; j + 3 < d; j += 4) {
    int s0 = csr[start + j], s1 = csr[start + j + 1];
    int s2 = csr[start + j + 2], s3 = csr[start + j + 3];
    a0 += p[(size_t)s0 * 16 + dd]; a1 += p[(size_t)s1 * 16 + dd];
    a2 += p[(size_t)s2 * 16 + dd]; a3 += p[(size_t)s3 * 16 + dd];
  }
  for (; j < d; ++j) a0 += p[(size_t)csr[start + j] * 16 + dd];
  float inv = (d > 0) ? 1.f / (float)d : 0.f;
  out[t] = ((((a0 + a1) + (a2 + a3)) + ((a4 + a5) + (a6 + a7)))) * inv + out[t] + b2[dd];
}

extern "C" void kernel_launch(void* const* d_in, const int* in_sizes, int n_in,
                              void* d_out, int out_size, void* d_ws, size_t ws_size,
                              hipStream_t stream) {
  const float* x   = (const float*)d_in[0];
  const int*   ei  = (const int*)d_in[1];
  const float* W1l = (const float*)d_in[2];
  const float* W1r = (const float*)d_in[3];
  const float* b1  = (const float*)d_in[4];
  const float* W2l = (const float*)d_in[5];
  const float* W2r = (const float*)d_in[6];
  const float* b2  = (const float*)d_in[7];
  float* out = (float*)d_out;

  int N = in_sizes[0] / 64;
  int E = in_sizes[1] / 2;
  const int* srcI = ei;
  const int* dstI = ei + E;

  int capN = (N + NB - 1) / NB;       // 391 (<512: fits 9-bit dl)
  int capE = E / NB + 1024;

  size_t off = 0;
  auto alloc = [&](size_t bytes) -> char* {
    char* r = (char*)d_ws + off;
    off = (off + bytes + 255) & ~(size_t)255;
    return r;
  };
  int*   deg    = (int*)alloc((size_t)N * 4);
  int*   rowoff = (int*)alloc((size_t)N * 4);
  int*   csr    = (int*)alloc((size_t)NB * capE * 4);
  int*   gcur   = (int*)alloc(NB * 4);
  float* h      = (float*)alloc((size_t)N * 64 * 4);
  float* p      = (float*)alloc((size_t)N * 16 * 4);
  int*   pairs  = (int*)h;            // overlay: pairs dead before h is written
  if (off > ws_size) return;
  if ((size_t)NB * capE * 4 > (size_t)N * 64 * 4) return;
  if (N > (1 << 17) || capN > (1 << 9)) return;  // packing validity

  hipMemsetAsync(gcur, 0, NB * 4, stream);
  k_part<<<(E + CHUNK - 1) / CHUNK, 256, 0, stream>>>(srcI, dstI, gcur, pairs, E, N, capN, capE);
  k_csr<<<NB, 512, 0, stream>>>(pairs, gcur, deg, rowoff, csr, N, capN, capE);

  // layer 1 (fused): h = relu(mean_agg(x)@W1l + x@W1r + b1)
  k_aggh<<<(N + 63) / 64, 256, 0, stream>>>(x, csr, rowoff, deg, W1l, W1r, b1, h, N);

  // layer 2 (transform-first): p = h@W2l, q = h@W2r (to d_out); out = mean_agg(p)+q+b2
  k_pq<<<(N + 127) / 128, 256, 0, stream>>>(h, W2l, W2r, p, out, N);
  k_agg16<<<(N * 16 + 255) / 256, 256, 0, stream>>>(p, csr, rowoff, deg, b2, out, N);
}

// Round 8
// 241.280 us; speedup vs baseline: 1.1296x; 1.1296x over previous
//
#include <hip/hip_runtime.h>
#include <hip/hip_fp16.h>

#define NB 256      // dst-range buckets
#define CHUNK 8192  // edges per partition block
// pack: code = (dl<<17)|src ; valid because N=100000<2^17 and capN=391<2^9

// ---------------- x -> fp16 copy (gather payload compression) ----------------
__global__ void k_cvt(const float* __restrict__ x, __half* __restrict__ xh, int total) {
  int i = (blockIdx.x * 256 + threadIdx.x) * 8;
  if (i >= total) return;
  float4 a = *(const float4*)(x + i);
  float4 b = *(const float4*)(x + i + 4);
  __half2* dst = (__half2*)(xh + i);
  dst[0] = __floats2half2_rn(a.x, a.y);
  dst[1] = __floats2half2_rn(a.z, a.w);
  dst[2] = __floats2half2_rn(b.x, b.y);
  dst[3] = __floats2half2_rn(b.z, b.w);
}

// ---------------- phase 1: partition edges into dst-range buckets ----------------
__global__ void k_part(const int* __restrict__ srcI, const int* __restrict__ dstI,
                       int* __restrict__ gcur, int* __restrict__ pairs,
                       int E, int N, int capN, int capE) {
  __shared__ int hist[NB];
  __shared__ int base[NB];
  __shared__ int cnt[NB];
  int tid = threadIdx.x;  // 256
  int e0 = blockIdx.x * CHUNK;
  int eend = min(e0 + CHUNK, E);
  hist[tid] = 0;
  __syncthreads();
  for (int e = e0 + tid; e < eend; e += 256) {
    int d = dstI[e];
    if ((unsigned)d < (unsigned)N) atomicAdd(&hist[d / capN], 1);
  }
  __syncthreads();
  base[tid] = tid * capE + atomicAdd(&gcur[tid], hist[tid]);
  cnt[tid] = 0;
  __syncthreads();
  for (int e = e0 + tid; e < eend; e += 256) {
    int d = dstI[e];
    int s = srcI[e];
    if ((unsigned)d < (unsigned)N && (unsigned)s < (unsigned)N) {
      int b = d / capN;
      int slot = base[b] + atomicAdd(&cnt[b], 1);
      if (slot < (b + 1) * capE)
        pairs[slot] = ((d - b * capN) << 17) | s;
    }
  }
}

// ---------------- phase 2: per-bucket CSR build ----------------
__launch_bounds__(512)
__global__ void k_csr(const int* __restrict__ pairs, const int* __restrict__ gcur,
                      int* __restrict__ deg, int* __restrict__ rowoff,
                      int* __restrict__ csr, int N, int capN, int capE) {
  __shared__ int hist[512];
  __shared__ int tmp[512];
  __shared__ int cur[512];
  int q = blockIdx.x;
  int tid = threadIdx.x;
  int nloc = N - q * capN;
  if (nloc > capN) nloc = capN;
  int base = q * capE;
  int cnt = gcur[q];
  if (cnt > capE) cnt = capE;
  int qbase = q * capN;
  hist[tid] = 0;
  __syncthreads();
  for (int e = tid; e < cnt; e += 512) {
    int code = pairs[base + e];
    int dl = (unsigned)code >> 17;
    if (dl < nloc) atomicAdd(&hist[dl], 1);
  }
  __syncthreads();
  int v = hist[tid];
  tmp[tid] = v;
  __syncthreads();
  for (int off = 1; off < 512; off <<= 1) {
    int t = (tid >= off) ? tmp[tid - off] : 0;
    __syncthreads();
    tmp[tid] += t;
    __syncthreads();
  }
  int ex = tmp[tid] - v;
  cur[tid] = ex;
  if (tid < nloc) {
    int i = qbase + tid;
    deg[i] = v;
    rowoff[i] = base + ex;
  }
  __syncthreads();
  for (int e = tid; e < cnt; e += 512) {
    int code = pairs[base + e];
    int dl = (unsigned)code >> 17;
    if (dl < nloc) {
      int pos = atomicAdd(&cur[dl], 1);
      csr[base + pos] = code & 0x1FFFF;
    }
  }
}

// ---------------- mean aggregate 64-dim from fp16: wave per node, lane per dim ----
__global__ void k_agg64(const __half* __restrict__ xh, const int* __restrict__ csr,
                        const int* __restrict__ rowoff, const int* __restrict__ deg,
                        float* __restrict__ m, int n) {
  int w = (blockIdx.x * blockDim.x + threadIdx.x) >> 6;
  int lane = threadIdx.x & 63;
  if (w >= n) return;
  int start = __builtin_amdgcn_readfirstlane(rowoff[w]);
  int d = __builtin_amdgcn_readfirstlane(deg[w]);
  float a0 = 0.f, a1 = 0.f, a2 = 0.f, a3 = 0.f;
  float a4 = 0.f, a5 = 0.f, a6 = 0.f, a7 = 0.f;
  int j = 0;
  for (; j + 7 < d; j += 8) {
    int s0 = csr[start + j], s1 = csr[start + j + 1];
    int s2 = csr[start + j + 2], s3 = csr[start + j + 3];
    int s4 = csr[start + j + 4], s5 = csr[start + j + 5];
    int s6 = csr[start + j + 6], s7 = csr[start + j + 7];
    a0 += __half2float(xh[(size_t)s0 * 64 + lane]);
    a1 += __half2float(xh[(size_t)s1 * 64 + lane]);
    a2 += __half2float(xh[(size_t)s2 * 64 + lane]);
    a3 += __half2float(xh[(size_t)s3 * 64 + lane]);
    a4 += __half2float(xh[(size_t)s4 * 64 + lane]);
    a5 += __half2float(xh[(size_t)s5 * 64 + lane]);
    a6 += __half2float(xh[(size_t)s6 * 64 + lane]);
    a7 += __half2float(xh[(size_t)s7 * 64 + lane]);
  }
  for (; j + 3 < d; j += 4) {
    int s0 = csr[start + j], s1 = csr[start + j + 1];
    int s2 = csr[start + j + 2], s3 = csr[start + j + 3];
    a0 += __half2float(xh[(size_t)s0 * 64 + lane]);
    a1 += __half2float(xh[(size_t)s1 * 64 + lane]);
    a2 += __half2float(xh[(size_t)s2 * 64 + lane]);
    a3 += __half2float(xh[(size_t)s3 * 64 + lane]);
  }
  for (; j < d; ++j) a0 += __half2float(xh[(size_t)csr[start + j] * 64 + lane]);
  float inv = (d > 0) ? 1.f / (float)d : 0.f;
  m[(size_t)w * 64 + lane] = (((a0 + a1) + (a2 + a3)) + ((a4 + a5) + (a6 + a7))) * inv;
}

// ---------------- layer1 GEMM: h = relu([m|x] @ [W1l;W1r] + b1) -------------------
__launch_bounds__(256, 4)
__global__ void k_h(const float* __restrict__ m, const float* __restrict__ x,
                    const float* __restrict__ Wl, const float* __restrict__ Wr,
                    const float* __restrict__ b1, float* __restrict__ h, int n) {
  __shared__ float sAT[32 * 68];   // [k][row], stride 68 (16B-aligned)
  __shared__ float sW[32 * 64];    // [k][col]
  int tid = threadIdx.x;
  int row0 = blockIdx.x * 64;
  int colT = tid & 15;
  int rowT = tid >> 4;
  float acc[4][4];
#pragma unroll
  for (int r = 0; r < 4; ++r)
#pragma unroll
    for (int c = 0; c < 4; ++c) acc[r][c] = 0.f;

  for (int kt = 0; kt < 4; ++kt) {
    const float* asrc = (kt < 2) ? m : x;
    const float* wsrc = (kt < 2) ? Wl : Wr;
    int ko = (kt & 1) * 32;
    __syncthreads();
    {
      int f = tid;
#pragma unroll
      for (int i = 0; i < 2; ++i, f += 256) {
        int r = f >> 3, kq = f & 7;
        int rr = row0 + r; if (rr > n - 1) rr = n - 1;
        float4 v = *(const float4*)(asrc + (size_t)rr * 64 + ko + kq * 4);
        sAT[(kq * 4 + 0) * 68 + r] = v.x;
        sAT[(kq * 4 + 1) * 68 + r] = v.y;
        sAT[(kq * 4 + 2) * 68 + r] = v.z;
        sAT[(kq * 4 + 3) * 68 + r] = v.w;
      }
      int g = tid;
#pragma unroll
      for (int i = 0; i < 2; ++i, g += 256) {
        int wr = g >> 4, cq = g & 15;
        float4 v = *(const float4*)(wsrc + (size_t)(ko + wr) * 64 + cq * 4);
        *(float4*)&sW[wr * 64 + cq * 4] = v;
      }
    }
    __syncthreads();
#pragma unroll 4
    for (int k = 0; k < 32; ++k) {
      float4 a = *(const float4*)&sAT[k * 68 + rowT * 4];
      float4 w = *(const float4*)&sW[k * 64 + colT * 4];
      acc[0][0] += a.x * w.x; acc[0][1] += a.x * w.y; acc[0][2] += a.x * w.z; acc[0][3] += a.x * w.w;
      acc[1][0] += a.y * w.x; acc[1][1] += a.y * w.y; acc[1][2] += a.y * w.z; acc[1][3] += a.y * w.w;
      acc[2][0] += a.z * w.x; acc[2][1] += a.z * w.y; acc[2][2] += a.z * w.z; acc[2][3] += a.z * w.w;
      acc[3][0] += a.w * w.x; acc[3][1] += a.w * w.y; acc[3][2] += a.w * w.z; acc[3][3] += a.w * w.w;
    }
  }
  float4 bb = *(const float4*)(b1 + colT * 4);
#pragma unroll
  for (int r = 0; r < 4; ++r) {
    int row = row0 + rowT * 4 + r;
    if (row < n) {
      float4 o;
      o.x = fmaxf(acc[r][0] + bb.x, 0.f);
      o.y = fmaxf(acc[r][1] + bb.y, 0.f);
      o.z = fmaxf(acc[r][2] + bb.z, 0.f);
      o.w = fmaxf(acc[r][3] + bb.w, 0.f);
      *(float4*)(h + (size_t)row * 64 + colT * 4) = o;
    }
  }
}

// ---------------- layer2 GEMM: p16 = half(h@W2l), q = h@W2r (to d_out) ------------
__launch_bounds__(256, 4)
__global__ void k_pq(const float* __restrict__ h, const float* __restrict__ W2l,
                     const float* __restrict__ W2r, __half* __restrict__ p16,
                     float* __restrict__ q, int n) {
  __shared__ float sAT[32 * 132];
  __shared__ float sW[32 * 32];
  int tid = threadIdx.x;
  int row0 = blockIdx.x * 128;
  int colT = tid & 7;
  int rowT = tid >> 3;
  float acc[4][4];
#pragma unroll
  for (int r = 0; r < 4; ++r)
#pragma unroll
    for (int c = 0; c < 4; ++c) acc[r][c] = 0.f;

  for (int kt = 0; kt < 2; ++kt) {
    int ko = kt * 32;
    __syncthreads();
    {
      int f = tid;
#pragma unroll
      for (int i = 0; i < 4; ++i, f += 256) {
        int r = f >> 3, kq = f & 7;
        int rr = row0 + r; if (rr > n - 1) rr = n - 1;
        float4 v = *(const float4*)(h + (size_t)rr * 64 + ko + kq * 4);
        sAT[(kq * 4 + 0) * 132 + r] = v.x;
        sAT[(kq * 4 + 1) * 132 + r] = v.y;
        sAT[(kq * 4 + 2) * 132 + r] = v.z;
        sAT[(kq * 4 + 3) * 132 + r] = v.w;
      }
      int wr = tid >> 3, cq = tid & 7;
      const float* wsrc = (cq < 4) ? W2l : W2r;
      int cc = (cq & 3) * 4;
      float4 v = *(const float4*)(wsrc + (size_t)(ko + wr) * 16 + cc);
      *(float4*)&sW[wr * 32 + cq * 4] = v;
    }
    __syncthreads();
#pragma unroll 4
    for (int k = 0; k < 32; ++k) {
      float4 a = *(const float4*)&sAT[k * 132 + rowT * 4];
      float4 w = *(const float4*)&sW[k * 32 + colT * 4];
      acc[0][0] += a.x * w.x; acc[0][1] += a.x * w.y; acc[0][2] += a.x * w.z; acc[0][3] += a.x * w.w;
      acc[1][0] += a.y * w.x; acc[1][1] += a.y * w.y; acc[1][2] += a.y * w.z; acc[1][3] += a.y * w.w;
      acc[2][0] += a.z * w.x; acc[2][1] += a.z * w.y; acc[2][2] += a.z * w.z; acc[2][3] += a.z * w.w;
      acc[3][0] += a.w * w.x; acc[3][1] += a.w * w.y; acc[3][2] += a.w * w.z; acc[3][3] += a.w * w.w;
    }
  }
#pragma unroll
  for (int r = 0; r < 4; ++r) {
    int row = row0 + rowT * 4 + r;
    if (row < n) {
      if (colT < 4) {
        __half2* dst = (__half2*)(p16 + (size_t)row * 16 + colT * 4);
        dst[0] = __floats2half2_rn(acc[r][0], acc[r][1]);
        dst[1] = __floats2half2_rn(acc[r][2], acc[r][3]);
      } else {
        *(float4*)(q + (size_t)row * 16 + (colT - 4) * 4) =
            make_float4(acc[r][0], acc[r][1], acc[r][2], acc[r][3]);
      }
    }
  }
}

// ---------------- mean aggregate 16-dim (fp16) + epilogue -------------------------
__global__ void k_agg16(const __half* __restrict__ p16, const int* __restrict__ csr,
                        const int* __restrict__ rowoff, const int* __restrict__ deg,
                        const float* __restrict__ b2, float* __restrict__ out, int n) {
  int t = blockIdx.x * blockDim.x + threadIdx.x;
  int i = t >> 4;
  int dd = t & 15;
  if (i >= n) return;
  int start = rowoff[i];
  int d = deg[i];
  float a0 = 0.f, a1 = 0.f, a2 = 0.f, a3 = 0.f;
  float a4 = 0.f, a5 = 0.f, a6 = 0.f, a7 = 0.f;
  int j = 0;
  for (; j + 7 < d; j += 8) {
    int s0 = csr[start + j], s1 = csr[start + j + 1];
    int s2 = csr[start + j + 2], s3 = csr[start + j + 3];
    int s4 = csr[start + j + 4], s5 = csr[start + j + 5];
    int s6 = csr[start + j + 6], s7 = csr[start + j + 7];
    a0 += __half2float(p16[(size_t)s0 * 16 + dd]);
    a1 += __half2float(p16[(size_t)s1 * 16 + dd]);
    a2 += __half2float(p16[(size_t)s2 * 16 + dd]);
    a3 += __half2float(p16[(size_t)s3 * 16 + dd]);
    a4 += __half2float(p16[(size_t)s4 * 16 + dd]);
    a5 += __half2float(p16[(size_t)s5 * 16 + dd]);
    a6 += __half2float(p16[(size_t)s6 * 16 + dd]);
    a7 += __half2float(p16[(size_t)s7 * 16 + dd]);
  }
  for (; j + 3 < d; j += 4) {
    int s0 = csr[start + j], s1 = csr[start + j + 1];
    int s2 = csr[start + j + 2], s3 = csr[start + j + 3];
    a0 += __half2float(p16[(size_t)s0 * 16 + dd]);
    a1 += __half2float(p16[(size_t)s1 * 16 + dd]);
    a2 += __half2float(p16[(size_t)s2 * 16 + dd]);
    a3 += __half2float(p16[(size_t)s3 * 16 + dd]);
  }
  for (; j < d; ++j) a0 += __half2float(p16[(size_t)csr[start + j] * 16 + dd]);
  float inv = (d > 0) ? 1.f / (float)d : 0.f;
  out[t] = ((((a0 + a1) + (a2 + a3)) + ((a4 + a5) + (a6 + a7)))) * inv + out[t] + b2[dd];
}

extern "C" void kernel_launch(void* const* d_in, const int* in_sizes, int n_in,
                              void* d_out, int out_size, void* d_ws, size_t ws_size,
                              hipStream_t stream) {
  const float* x   = (const float*)d_in[0];
  const int*   ei  = (const int*)d_in[1];
  const float* W1l = (const float*)d_in[2];
  const float* W1r = (const float*)d_in[3];
  const float* b1  = (const float*)d_in[4];
  const float* W2l = (const float*)d_in[5];
  const float* W2r = (const float*)d_in[6];
  const float* b2  = (const float*)d_in[7];
  float* out = (float*)d_out;

  int N = in_sizes[0] / 64;
  int E = in_sizes[1] / 2;
  const int* srcI = ei;
  const int* dstI = ei + E;

  int capN = (N + NB - 1) / NB;       // 391 (<512: fits 9-bit dl)
  int capE = E / NB + 1024;

  size_t off = 0;
  auto alloc = [&](size_t bytes) -> char* {
    char* r = (char*)d_ws + off;
    off = (off + bytes + 255) & ~(size_t)255;
    return r;
  };
  int*    deg    = (int*)alloc((size_t)N * 4);
  int*    rowoff = (int*)alloc((size_t)N * 4);
  int*    csr    = (int*)alloc((size_t)NB * capE * 4);
  int*    gcur   = (int*)alloc(NB * 4);
  __half* xh     = (__half*)alloc((size_t)N * 64 * 2);
  float*  m      = (float*)alloc((size_t)N * 64 * 4);
  float*  h      = (float*)alloc((size_t)N * 64 * 4);
  __half* p16    = (__half*)alloc((size_t)N * 16 * 2);
  int*    pairs  = (int*)h;           // overlay: pairs dead before h is written
  if (off > ws_size) return;          // visible failure if ws too small
  if ((size_t)NB * capE * 4 > (size_t)N * 64 * 4) return;
  if (N > (1 << 17) || capN > (1 << 9)) return;  // packing validity

  hipMemsetAsync(gcur, 0, NB * 4, stream);
  k_cvt<<<(N * 64 + 2047) / 2048, 256, 0, stream>>>(x, xh, N * 64);
  k_part<<<(E + CHUNK - 1) / CHUNK, 256, 0, stream>>>(srcI, dstI, gcur, pairs, E, N, capN, capE);
  k_csr<<<NB, 512, 0, stream>>>(pairs, gcur, deg, rowoff, csr, N, capN, capE);

  // layer 1: m = mean_agg(xh); h = relu(m@W1l + x@W1r + b1)
  k_agg64<<<(N * 64 + 255) / 256, 256, 0, stream>>>(xh, csr, rowoff, deg, m, N);
  k_h<<<(N + 63) / 64, 256, 0, stream>>>(m, x, W1l, W1r, b1, h, N);

  // layer 2 (transform-first): p16 = h@W2l (fp16), q = h@W2r (to d_out)
  k_pq<<<(N + 127) / 128, 256, 0, stream>>>(h, W2l, W2r, p16, out, N);
  k_agg16<<<(N * 16 + 255) / 256, 256, 0, stream>>>(p16, csr, rowoff, deg, b2, out, N);
}